// Round 3
// baseline (490.444 us; speedup 1.0000x reference)
//
#include <hip/hip_runtime.h>
#include <math.h>

#define Bdim 16
#define Mdim 4096
#define Tdim 4
#define Ddim 256
#define Vdim 40000
#define CONVMAX 512
#define MT 64

// ---------------------------------------------------------------------------
// init: out_uf = query_vector    grid: B blocks, 256 threads
// ---------------------------------------------------------------------------
__global__ void init_kernel(const float* __restrict__ qv, float* __restrict__ uf) {
    int b = blockIdx.x, i = threadIdx.x;
    uf[(size_t)b * Ddim + i] = qv[(size_t)b * Ddim + i];
}

// ---------------------------------------------------------------------------
// qk: recompute e_k(row) by gather; logits[row] = gp[row] * dot(e_k, uf[b])
// grid: B*M/16 blocks, 256 threads (wave handles 4 consecutive rows)
// ---------------------------------------------------------------------------
__global__ void qk_kernel(const int* __restrict__ story, const int* __restrict__ kb_len,
                          const int* __restrict__ conv_len, const float* __restrict__ hist,
                          const float* __restrict__ tab, const float* __restrict__ uf,
                          const float* __restrict__ gp, float* __restrict__ logits) {
    int tid = threadIdx.x, wave = tid >> 6, lane = tid & 63;
    int row0 = blockIdx.x * 16 + wave * 4;
    int b = row0 >> 12;                        // M = 4096 rows per b
    int d4 = lane * 4;
    const float4 uv = *(const float4*)(uf + (size_t)b * Ddim + d4);
    int kb = kb_len[b], cl = conv_len[b];
#pragma unroll
    for (int r = 0; r < 4; ++r) {
        int row = row0 + r;
        int m = row & (Mdim - 1);
        const int* st = story + (size_t)row * Tdim;
        float4 acc = make_float4(0.f, 0.f, 0.f, 0.f);
#pragma unroll
        for (int t = 0; t < Tdim; ++t) {
            const float4 v = *(const float4*)(tab + (size_t)st[t] * Ddim + d4);
            acc.x += v.x; acc.y += v.y; acc.z += v.z; acc.w += v.w;
        }
        if (m >= kb && m < kb + cl) {
            const float4 h = *(const float4*)(hist + ((size_t)b * CONVMAX + (m - kb)) * Ddim + d4);
            acc.x += h.x; acc.y += h.y; acc.z += h.z; acc.w += h.w;
        }
        float p = acc.x * uv.x + acc.y * uv.y + acc.z * uv.z + acc.w * uv.w;
#pragma unroll
        for (int off = 32; off > 0; off >>= 1) p += __shfl_xor(p, off, 64);
        if (lane == 0) logits[row] = p * gp[row];
    }
}

// ---------------------------------------------------------------------------
// per-batch softmax stats (max, 1/sumexp)   grid: B blocks, 256 threads
// ---------------------------------------------------------------------------
__global__ void stats_kernel(const float* __restrict__ logits, float* __restrict__ maxv,
                             float* __restrict__ rsum) {
    int b = blockIdx.x, tid = threadIdx.x;
    __shared__ float sh[256];
    const float* lg = logits + (size_t)b * Mdim;
    float mx = -INFINITY;
    for (int i = tid; i < Mdim; i += 256) mx = fmaxf(mx, lg[i]);
    sh[tid] = mx; __syncthreads();
    for (int s = 128; s > 0; s >>= 1) { if (tid < s) sh[tid] = fmaxf(sh[tid], sh[tid + s]); __syncthreads(); }
    float bm = sh[0]; __syncthreads();
    float sm = 0.f;
    for (int i = tid; i < Mdim; i += 256) sm += expf(lg[i] - bm);
    sh[tid] = sm; __syncthreads();
    for (int s = 128; s > 0; s >>= 1) { if (tid < s) sh[tid] += sh[tid + s]; __syncthreads(); }
    if (tid == 0) { maxv[b] = bm; rsum[b] = 1.0f / sh[0]; }
}

// ---------------------------------------------------------------------------
// att: recompute e_{k+1}(row) by gather; prob = exp(logit-max)*rsum * gp;
//      uf[b,:] += sum_m prob * e;  optionally write e to out_m (k=3) and
//      the gp-free softmax to out_psoft (last hop).
// grid: B*(M/MT) blocks, 256 threads (wave per row, float4 per lane)
// ---------------------------------------------------------------------------
__global__ void att_kernel(const int* __restrict__ story, const int* __restrict__ kb_len,
                           const int* __restrict__ conv_len, const float* __restrict__ hist,
                           const float* __restrict__ tab, const float* __restrict__ logits,
                           const float* __restrict__ maxv, const float* __restrict__ rsum,
                           const float* __restrict__ gp,
                           float* __restrict__ uf_acc, float* __restrict__ out_m,
                           float* __restrict__ out_psoft) {
    int bid = blockIdx.x;
    int b  = bid / (Mdim / MT);
    int m0 = (bid % (Mdim / MT)) * MT;
    int tid = threadIdx.x, wave = tid >> 6, lane = tid & 63;
    int d4 = lane * 4;
    __shared__ float prob[MT];
    __shared__ float4 red[4][64];
    if (tid < MT) {
        size_t row = (size_t)b * Mdim + m0 + tid;
        float pn = expf(logits[row] - maxv[b]) * rsum[b];
        if (out_psoft) out_psoft[row] = pn;
        prob[tid] = pn * gp[row];
    }
    __syncthreads();
    int kb = kb_len[b], cl = conv_len[b];
    float4 acc = make_float4(0.f, 0.f, 0.f, 0.f);
#pragma unroll 4
    for (int mm = wave; mm < MT; mm += 4) {
        int m = m0 + mm;
        size_t row = (size_t)b * Mdim + m;
        const int* st = story + row * Tdim;
        float4 v = make_float4(0.f, 0.f, 0.f, 0.f);
#pragma unroll
        for (int t = 0; t < Tdim; ++t) {
            const float4 w = *(const float4*)(tab + (size_t)st[t] * Ddim + d4);
            v.x += w.x; v.y += w.y; v.z += w.z; v.w += w.w;
        }
        if (m >= kb && m < kb + cl) {
            const float4 h = *(const float4*)(hist + ((size_t)b * CONVMAX + (m - kb)) * Ddim + d4);
            v.x += h.x; v.y += h.y; v.z += h.z; v.w += h.w;
        }
        if (out_m) *(float4*)(out_m + row * Ddim + d4) = v;
        float p = prob[mm];
        acc.x += p * v.x; acc.y += p * v.y; acc.z += p * v.z; acc.w += p * v.w;
    }
    red[wave][lane] = acc;
    __syncthreads();
    if (wave == 0) {
        float4 a0 = red[0][lane], a1 = red[1][lane], a2 = red[2][lane], a3 = red[3][lane];
        float* dst = uf_acc + (size_t)b * Ddim + d4;
        atomicAdd(dst + 0, a0.x + a1.x + a2.x + a3.x);
        atomicAdd(dst + 1, a0.y + a1.y + a2.y + a3.y);
        atomicAdd(dst + 2, a0.z + a1.z + a2.z + a3.z);
        atomicAdd(dst + 3, a0.w + a1.w + a2.w + a3.w);
    }
}

extern "C" void kernel_launch(void* const* d_in, const int* in_sizes, int n_in,
                              void* d_out, int out_size, void* d_ws, size_t ws_size,
                              hipStream_t stream) {
    const int*   story        = (const int*)d_in[0];
    const int*   kb_len       = (const int*)d_in[1];
    const int*   conv_len     = (const int*)d_in[2];
    // d_in[3] (query), d_in[8..11] (Tg_w, Tg_b, FW_w, FW_b): dead w.r.t. outputs
    const float* hist         = (const float*)d_in[4];
    const float* query_vector = (const float*)d_in[5];
    const float* gp           = (const float*)d_in[6];
    const float* C_emb        = (const float*)d_in[7];

    float* out        = (float*)d_out;
    float* out_psoft  = out;                                   // B*M
    float* out_logits = out + (size_t)Bdim * Mdim;             // B*M
    float* out_uf     = out + 2 * (size_t)Bdim * Mdim;         // B*D
    float* out_m      = out + 2 * (size_t)Bdim * Mdim + (size_t)Bdim * Ddim; // B*M*D

    float* ws = (float*)d_ws;
    float* logits = ws;                            // B*M
    float* maxv   = logits + (size_t)Bdim * Mdim;  // B
    float* rsum   = maxv + Bdim;                   // B

    const size_t TAB = (size_t)Vdim * Ddim;
    const float* tab0 = C_emb;
    const float* tab1 = C_emb + TAB;
    const float* tab2 = C_emb + 2 * TAB;
    const float* tab3 = C_emb + 3 * TAB;

    const int QK_GRID  = Bdim * Mdim / 16;
    const int ATT_GRID = Bdim * (Mdim / MT);

    // uf = query_vector
    init_kernel<<<Bdim, Ddim, 0, stream>>>(query_vector, out_uf);

    // hop 0
    qk_kernel<<<QK_GRID, 256, 0, stream>>>(story, kb_len, conv_len, hist,
                                           tab0, query_vector, gp, logits);
    stats_kernel<<<Bdim, 256, 0, stream>>>(logits, maxv, rsum);
    att_kernel<<<ATT_GRID, 256, 0, stream>>>(story, kb_len, conv_len, hist,
                                             tab1, logits, maxv, rsum, gp,
                                             out_uf, nullptr, nullptr);
    // hop 1
    qk_kernel<<<QK_GRID, 256, 0, stream>>>(story, kb_len, conv_len, hist,
                                           tab1, out_uf, gp, logits);
    stats_kernel<<<Bdim, 256, 0, stream>>>(logits, maxv, rsum);
    att_kernel<<<ATT_GRID, 256, 0, stream>>>(story, kb_len, conv_len, hist,
                                             tab2, logits, maxv, rsum, gp,
                                             out_uf, nullptr, nullptr);
    // hop 2 (logits, psoft, out_m are outputs)
    qk_kernel<<<QK_GRID, 256, 0, stream>>>(story, kb_len, conv_len, hist,
                                           tab2, out_uf, gp, out_logits);
    stats_kernel<<<Bdim, 256, 0, stream>>>(out_logits, maxv, rsum);
    att_kernel<<<ATT_GRID, 256, 0, stream>>>(story, kb_len, conv_len, hist,
                                             tab3, out_logits, maxv, rsum, gp,
                                             out_uf, out_m, out_psoft);
}